// Round 15
// baseline (327.937 us; speedup 1.0000x reference)
//
#include <hip/hip_runtime.h>

// Problem constants
#define DIMX 2048
#define SEQ  2048
#define BATCH 2
#define NH   16
#define NKV  8
#define HD   128
#define MTOK (BATCH*SEQ)   // 4096 tokens
#define NQKV 4096          // GEMM1 output cols: 2048 Q + 1024 K + 1024 V
#define QKLD 3072          // qkv buffer stride (Q+K only; V goes to Vt)

typedef __bf16 bf16x8 __attribute__((ext_vector_type(8)));
typedef float  f32x4  __attribute__((ext_vector_type(4)));
typedef float  f32x16 __attribute__((ext_vector_type(16)));
typedef unsigned short u16x8 __attribute__((ext_vector_type(8)));
typedef unsigned short u16x4 __attribute__((ext_vector_type(4)));
typedef unsigned int   u32x4 __attribute__((ext_vector_type(4)));

__device__ __forceinline__ unsigned short f2bf(float f) {
    unsigned u = __builtin_bit_cast(unsigned, f);
    u += 0x7fffu + ((u >> 16) & 1u);            // RNE
    return (unsigned short)(u >> 16);
}
__device__ __forceinline__ float bf2f(unsigned short h) {
    unsigned u = ((unsigned)h) << 16;
    return __builtin_bit_cast(float, u);
}

__device__ __forceinline__ void gload16(const void* g, void* l) {
    __builtin_amdgcn_global_load_lds(
        (const __attribute__((address_space(1))) unsigned int*)g,
        (__attribute__((address_space(3))) unsigned int*)l, 16, 0, 0);
}

// ---------------- fp32 -> bf16 elementwise convert (8 elems/thread) ----------------
__global__ __launch_bounds__(256) void k_convert(const float* __restrict__ in,
                                                 unsigned short* __restrict__ out, int n8) {
    int i = blockIdx.x * 256 + threadIdx.x;
    if (i >= n8) return;
    f32x4 a = ((const f32x4*)in)[(size_t)i*2];
    f32x4 b = ((const f32x4*)in)[(size_t)i*2+1];
    u16x8 o;
    o[0]=f2bf(a[0]); o[1]=f2bf(a[1]); o[2]=f2bf(a[2]); o[3]=f2bf(a[3]);
    o[4]=f2bf(b[0]); o[5]=f2bf(b[1]); o[6]=f2bf(b[2]); o[7]=f2bf(b[3]);
    ((u16x8*)out)[i] = o;
}

// ---------------- fp32 KxN -> bf16 NxK transpose (64x64 tiles via LDS) ----------------
__global__ __launch_bounds__(256) void k_transpose(const float* __restrict__ W,
                                                   unsigned short* __restrict__ Wt,
                                                   int K, int N) {
    __shared__ unsigned short tile[64*65];
    int t = threadIdx.x;
    int n0 = blockIdx.x * 64, k0 = blockIdx.y * 64;
    #pragma unroll
    for (int i = 0; i < 16; ++i) {
        int idx = t + i*256, r = idx >> 6, c = idx & 63;
        tile[r*65+c] = f2bf(W[(size_t)(k0+r)*N + n0 + c]);
    }
    __syncthreads();
    #pragma unroll
    for (int i = 0; i < 16; ++i) {
        int idx = t + i*256, n = idx >> 6, k = idx & 63;
        Wt[(size_t)(n0+n)*K + k0 + k] = tile[k*65+n];
    }
}

// ---------------- 256-wide bf16 GEMM: BMx(NREP*64) tile, BK=64, 8 waves (2Mx4N) ----------------
template<int NREP, int MODE>
__global__ __launch_bounds__(512, 2) void k_gemm256(const unsigned short* __restrict__ A,
                                                    const unsigned short* __restrict__ Bt,
                                                    void* __restrict__ Cv,
                                                    unsigned short* __restrict__ Vt,
                                                    int M, int N, int K, int ldc) {
    constexpr int BN  = NREP * 64;     // 256 or 128
    constexpr int BWC = NREP * 16;     // per-wave col span
    __shared__ __align__(16) char As[2][32768];
    __shared__ __align__(16) char Bs[2][BN * 128];
    int bid = blockIdx.x;
    int rem = (bid & 7) * 32 + (bid >> 3);      // T1 bijective XCD swizzle (nwg=256)
    int bx = rem & 15, by = rem >> 4;
    int row0 = by * 256, col0 = bx * BN;
    int tid = threadIdx.x, wave = tid >> 6, lane = tid & 63;
    int wr = wave >> 2, wc = wave & 3;
    int g = lane >> 4, r16 = lane & 15;
    const char* Ab = (const char*)A;
    const char* Bb = (const char*)Bt;

    f32x4 acc[8][NREP] = {};

    auto STAGE = [&](int buf, int t) {
        int k0b = t * 128;                       // byte offset into K (64 elems * 2B)
        #pragma unroll
        for (int p = 0; p < 4; ++p) {
            int c = wave * 4 + p;
            int o = c * 1024 + lane * 16;
            int row = o >> 7;
            int colb = (o & 127) ^ ((row & 7) << 4);
            gload16(Ab + (size_t)(row0 + row) * (size_t)(K * 2) + k0b + colb, &As[buf][c * 1024]);
        }
        #pragma unroll
        for (int p = 0; p < NREP; ++p) {
            int c = wave * NREP + p;
            int o = c * 1024 + lane * 16;
            int row = o >> 7;
            int colb = (o & 127) ^ ((row & 7) << 4);
            gload16(Bb + (size_t)(col0 + row) * (size_t)(K * 2) + k0b + colb, &Bs[buf][c * 1024]);
        }
    };

    int nt = K >> 6;
    STAGE(0, 0);
    STAGE(1, 1);
    if constexpr (NREP == 4) asm volatile("s_waitcnt vmcnt(8)" ::: "memory");
    else                     asm volatile("s_waitcnt vmcnt(6)" ::: "memory");
    __builtin_amdgcn_s_barrier();

    for (int t = 0; t < nt; ++t) {
        int buf = t & 1;
        const char* AL = As[buf];
        const char* BL = Bs[buf];
        bf16x8 a0[4][2], a1[4][2], bfr[NREP][2];
        #pragma unroll
        for (int mi = 0; mi < 4; ++mi)
            #pragma unroll
            for (int s = 0; s < 2; ++s) {
                int r = wr*128 + mi*16 + r16;
                int o = r*128 + s*64 + g*16;
                a0[mi][s] = *(const bf16x8*)(AL + (o ^ ((r & 7) << 4)));
            }
        #pragma unroll
        for (int ni = 0; ni < NREP; ++ni)
            #pragma unroll
            for (int s = 0; s < 2; ++s) {
                int r = wc*BWC + ni*16 + r16;
                int o = r*128 + s*64 + g*16;
                bfr[ni][s] = *(const bf16x8*)(BL + (o ^ ((r & 7) << 4)));
            }
        __builtin_amdgcn_s_setprio(1);
        #pragma unroll
        for (int mi = 0; mi < 4; ++mi)
            #pragma unroll
            for (int ni = 0; ni < NREP; ++ni)
                #pragma unroll
                for (int s = 0; s < 2; ++s)
                    acc[mi][ni] = __builtin_amdgcn_mfma_f32_16x16x32_bf16(a0[mi][s], bfr[ni][s], acc[mi][ni], 0, 0, 0);
        __builtin_amdgcn_s_setprio(0);
        #pragma unroll
        for (int mi = 0; mi < 4; ++mi)
            #pragma unroll
            for (int s = 0; s < 2; ++s) {
                int r = wr*128 + 64 + mi*16 + r16;
                int o = r*128 + s*64 + g*16;
                a1[mi][s] = *(const bf16x8*)(AL + (o ^ ((r & 7) << 4)));
            }
        asm volatile("s_waitcnt lgkmcnt(0)" ::: "memory");
        __builtin_amdgcn_sched_barrier(0);
        __builtin_amdgcn_s_barrier();            // barrier A: block-wide done reading buf
        if (t + 2 < nt) STAGE(buf, t + 2);       // overwrite freed buffer (loads fly under MFMA)
        __builtin_amdgcn_sched_barrier(0);
        __builtin_amdgcn_s_setprio(1);
        #pragma unroll
        for (int mi = 0; mi < 4; ++mi)
            #pragma unroll
            for (int ni = 0; ni < NREP; ++ni)
                #pragma unroll
                for (int s = 0; s < 2; ++s)
                    acc[mi+4][ni] = __builtin_amdgcn_mfma_f32_16x16x32_bf16(a1[mi][s], bfr[ni][s], acc[mi+4][ni], 0, 0, 0);
        __builtin_amdgcn_s_setprio(0);
        if (t + 2 < nt) {
            if constexpr (NREP == 4) asm volatile("s_waitcnt vmcnt(8)" ::: "memory");
            else                     asm volatile("s_waitcnt vmcnt(6)" ::: "memory");
        } else {
            asm volatile("s_waitcnt vmcnt(0)" ::: "memory");
        }
        __builtin_amdgcn_s_barrier();            // barrier B: K-tile t+1 data landed everywhere
    }

    // epilogue
    #pragma unroll
    for (int mi = 0; mi < 8; ++mi)
        #pragma unroll
        for (int ni = 0; ni < NREP; ++ni) {
            if (MODE == 0 && col0 >= 3072) {
                int vcol = col0 + wc*BWC + ni*16 + r16 - 3072;
                int d = vcol & 127, kh = vcol >> 7;
                int row = row0 + wr*128 + mi*16 + g*4;
                int b = row >> 11, s = row & (SEQ-1);
                u16x4 pk;
                #pragma unroll
                for (int rr = 0; rr < 4; ++rr) pk[rr] = f2bf(acc[mi][ni][rr]);
                *(u16x4*)&Vt[((size_t)(b*NKV + kh)*HD + d)*SEQ + s] = pk;
            } else {
                #pragma unroll
                for (int rr = 0; rr < 4; ++rr) {
                    int row = row0 + wr*128 + mi*16 + g*4 + rr;
                    int col = col0 + wc*BWC + ni*16 + r16;
                    float v = acc[mi][ni][rr];
                    if (MODE == 1) ((float*)Cv)[(size_t)row*ldc + col] = v;
                    else ((unsigned short*)Cv)[(size_t)row*ldc + col] = f2bf(v);
                }
            }
        }
}

// ---------------- RoPE in place; Q additionally pre-scaled by rsqrt(128)*log2(e) ----------------
__global__ __launch_bounds__(256) void k_rope(unsigned short* __restrict__ qkv) {
    int tid = blockIdx.x * 256 + threadIdx.x;   // MTOK*(NH+NKV)*64 threads
    int i    = tid & 63;                        // rotation pair index
    int rest = tid >> 6;
    int head = rest % (NH + NKV);
    int tok  = rest / (NH + NKV);
    int pos  = tok & (SEQ - 1);
    size_t base = (size_t)tok * QKLD + head*HD;
    float x1 = bf2f(qkv[base + i]);
    float x2 = bf2f(qkv[base + i + 64]);
    float inv = exp2f(-0.20762050593046014f * (float)i);   // 10000^(-i/64)
    float ang = (float)pos * inv;
    float s, c;
    sincosf(ang, &s, &c);
    float sc = (head < NH) ? 0.12754984523341717f : 1.0f;  // rsqrt(128)*log2(e) folded into Q
    qkv[base + i]      = f2bf((x1*c - x2*s) * sc);
    qkv[base + i + 64] = f2bf((x2*c + x1*s) * sc);
}

// ---------------- causal GQA flash attention v8: R10 core + split-KV for long chunks ----------------
// Grid 768 x 256 thr (4 waves), 2 blocks/CU (64KB LDS). Decode per XCD (96 slots = 4 bh x 24):
//   s24 in [0,16): SPLIT half of qt = 15-(s24>>1), ks = s24&1  (kv tiles [0,nt/2) / [nt/2,nt))
//   s24 in [16,24): UNSPLIT qt = 23-s24 in [0,8)
// Max block 17 tiles (was 32) -> makespan ~halved. Split blocks write partial (bf16 acc,
// f32 m,l in log2 units) to dead ws (xb region), threadfence, atomicAdd pair flag; second
// arriver merges (both sides bf16-rounded -> result independent of arrival order) and writes.
// Per-tile compute/staging/sync identical to validated R10 kernel.
__global__ __launch_bounds__(256, 2) void k_attn(const unsigned short* __restrict__ qkv,
                                                 const unsigned short* __restrict__ Vt,
                                                 unsigned short* __restrict__ attn_out,
                                                 char* __restrict__ partials,
                                                 int* __restrict__ flags) {
    __shared__ __align__(16) char KVs[2][32768];   // [buf]: K [64][128] @256B rows | V [128][64] @128B rows
    __shared__ int oldFlag;
    int bid = blockIdx.x;
    int xcd = bid & 7, slot = bid >> 3;            // 96 slots per XCD
    int grp = slot / 24, s24 = slot % 24;
    int bh  = xcd * 4 + grp;                       // [0,32)
    int qt, ks; bool split;
    if (s24 < 16) { split = true;  qt = 15 - (s24 >> 1); ks = s24 & 1; }
    else          { split = false; qt = 23 - s24;        ks = 0;       }
    int b = bh >> 4, h = bh & 15, kvh = h >> 1;
    int tid = threadIdx.x, wave = tid >> 6, lane = tid & 63;
    int l31 = lane & 31, hi = lane >> 5;
    int ntf = 2*qt + 2;                            // full chunk tiles (even)
    int vbeg = (split && ks) ? (ntf >> 1) : 0;
    int vend = (split && !ks) ? (ntf >> 1) : ntf;
    int q0w = qt*128 + wave*32;
    int qg  = q0w + l31;
    const unsigned short* qbase = qkv + (size_t)(b*SEQ)*QKLD;
    const char* kbase = (const char*)(qbase + DIMX + kvh*HD);
    const char* vbase = (const char*)(Vt + ((size_t)(b*NKV + kvh)*HD)*SEQ);

    bf16x8 qf[8];
    {
        const unsigned short* qr = qbase + (size_t)qg*QKLD + h*HD;
        #pragma unroll
        for (int s2 = 0; s2 < 8; ++s2) qf[s2] = *(const bf16x8*)(qr + s2*16 + hi*8);
    }

    f32x16 acc[4] = {};                            // O^T: d = 32dt + (r&3)+8(r>>2)+4hi, q = l31
    float mrow = -1e30f, lrow = 0.f;

    auto STAGE = [&](int v, int buf) {
        int kv0 = v * 64;
        char* KL = KVs[buf];
        char* VL = KL + 16384;
        #pragma unroll
        for (int pp = 0; pp < 4; ++pp) {
            int c = wave*4 + pp;
            int row  = c*4 + (lane >> 4);
            int colb = ((lane & 15) * 16) ^ ((row & 7) << 4);
            gload16(kbase + (size_t)(kv0 + row)*(QKLD*2) + colb, KL + c*1024);
            int d    = c*8 + (lane >> 3);
            int colv = ((lane & 7) * 16) ^ ((d & 7) << 4);
            gload16(vbase + (size_t)d*(SEQ*2) + (size_t)kv0*2 + colv, VL + c*1024);
        }
    };

    STAGE(vbeg, vbeg & 1);
    asm volatile("s_waitcnt vmcnt(0)" ::: "memory");
    __syncthreads();

    for (int v = vbeg; v < vend; ++v) {
        int buf = v & 1;
        int kv0 = v * 64;
        if (v + 1 < vend) STAGE(v + 1, buf ^ 1);    // loads fly under this tile's compute
        const char* KL = KVs[buf];
        const char* VL = KL + 16384;
        if (kv0 <= q0w + 31) {
            f32x16 st0 = {}, st1 = {};
            const char* kr0 = KL + l31*256;
            const char* kr1 = KL + (32 + l31)*256;
            unsigned sw = (unsigned)((l31 & 7) << 4);
            __builtin_amdgcn_s_setprio(1);
            #pragma unroll
            for (int s2 = 0; s2 < 8; ++s2) {
                unsigned off = (unsigned)(s2*32 + hi*16);
                bf16x8 kf0 = *(const bf16x8*)(kr0 + (off ^ sw));
                bf16x8 kf1 = *(const bf16x8*)(kr1 + (off ^ sw));
                st0 = __builtin_amdgcn_mfma_f32_32x32x16_bf16(kf0, qf[s2], st0, 0, 0, 0);
                st1 = __builtin_amdgcn_mfma_f32_32x32x16_bf16(kf1, qf[s2], st1, 0, 0, 0);
            }
            __builtin_amdgcn_s_setprio(0);
            if (kv0 + 63 > q0w) {
                #pragma unroll
                for (int r = 0; r < 16; ++r) {
                    int kvr = kv0 + (r & 3) + 8*(r >> 2) + 4*hi;
                    st0[r] = (kvr      <= qg) ? st0[r] : -1e30f;
                    st1[r] = (kvr + 32 <= qg) ? st1[r] : -1e30f;
                }
            }
            float mt = -1e30f;
            #pragma unroll
            for (int r = 0; r < 16; ++r) { mt = fmaxf(mt, st0[r]); mt = fmaxf(mt, st1[r]); }
            mt = fmaxf(mt, __shfl_xor(mt, 32, 64));
            if (!__all(mt - mrow <= 8.0f)) {
                float mn = fmaxf(mrow, mt);
                float corr = exp2f(mrow - mn);
                mrow = mn; lrow *= corr;
                #pragma unroll
                for (int dt = 0; dt < 4; ++dt)
                    #pragma unroll
                    for (int r = 0; r < 16; ++r) acc[dt][r] *= corr;
            }
            float rs = 0.f;
            #pragma unroll
            for (int r = 0; r < 16; ++r) {
                float p0 = exp2f(st0[r] - mrow); st0[r] = p0; rs += p0;
                float p1 = exp2f(st1[r] - mrow); st1[r] = p1; rs += p1;
            }
            lrow += rs + __shfl_xor(rs, 32, 64);
            #pragma unroll
            for (int t = 0; t < 2; ++t)
                #pragma unroll
                for (int ks2 = 0; ks2 < 2; ++ks2) {
                    const f32x16& stt = t ? st1 : st0;
                    int rb = ks2 * 8;
                    float p0 = stt[rb+0], p1 = stt[rb+1], p2 = stt[rb+2], p3 = stt[rb+3];
                    float p4 = stt[rb+4], p5 = stt[rb+5], p6 = stt[rb+6], p7 = stt[rb+7];
                    unsigned w0, w1, w2, w3;
                    asm("v_cvt_pk_bf16_f32 %0, %1, %2" : "=v"(w0) : "v"(p0), "v"(p1));
                    asm("v_cvt_pk_bf16_f32 %0, %1, %2" : "=v"(w1) : "v"(p2), "v"(p3));
                    asm("v_cvt_pk_bf16_f32 %0, %1, %2" : "=v"(w2) : "v"(p4), "v"(p5));
                    asm("v_cvt_pk_bf16_f32 %0, %1, %2" : "=v"(w3) : "v"(p6), "v"(p7));
                    asm("v_permlane32_swap_b32 %0, %1" : "+v"(w0), "+v"(w2));
                    asm("v_permlane32_swap_b32 %0, %1" : "+v"(w1), "+v"(w3));
                    u32x4 pu = {w0, w1, w2, w3};
                    bf16x8 pfrag = __builtin_bit_cast(bf16x8, pu);
                    int ks4 = t*2 + ks2;
                    __builtin_amdgcn_s_setprio(1);
                    #pragma unroll
                    for (int dt = 0; dt < 4; ++dt) {
                        int d = dt*32 + l31;
                        bf16x8 vf = *(const bf16x8*)(VL + d*128 +
                                     (((unsigned)(ks4*32 + hi*16)) ^ ((unsigned)((d & 7) << 4))));
                        acc[dt] = __builtin_amdgcn_mfma_f32_32x32x16_bf16(vf, pfrag, acc[dt], 0, 0, 0);
                    }
                    __builtin_amdgcn_s_setprio(0);
                }
        }
        asm volatile("s_waitcnt vmcnt(0)" ::: "memory");   // next tile landed block-wide
        __syncthreads();
    }

    int qw = wave*32 + l31;                        // q-row within the 128-row chunk
    if (!split) {
        float inv = 1.0f / lrow;
        #pragma unroll
        for (int dt = 0; dt < 4; ++dt)
            #pragma unroll
            for (int qd = 0; qd < 4; ++qd) {
                u16x4 o4;
                #pragma unroll
                for (int j = 0; j < 4; ++j) o4[j] = f2bf(acc[dt][qd*4 + j] * inv);
                *(u16x4*)&attn_out[(size_t)(b*SEQ + qg)*DIMX + h*HD + dt*32 + qd*8 + hi*4] = o4;
            }
        return;
    }

    // ---- split path: write partial (bf16 acc + f32 m,l), flag, maybe merge ----
    int pairIdx = bh*8 + (qt - 8);                 // [0,256)
    constexpr int SLOT = 33792;                    // 32768 acc-bf16 + 512 m + 512 l
    char* mySlot = partials + (size_t)(pairIdx*2 + ks) * SLOT;
    {
        unsigned short* pacc = (unsigned short*)mySlot;
        #pragma unroll
        for (int dt = 0; dt < 4; ++dt)
            #pragma unroll
            for (int qd = 0; qd < 4; ++qd) {
                u16x4 pk;
                #pragma unroll
                for (int j = 0; j < 4; ++j) pk[j] = f2bf(acc[dt][qd*4 + j]);
                *(u16x4*)&pacc[qw*128 + dt*32 + qd*8 + hi*4] = pk;
            }
        if (hi == 0) {
            ((float*)(mySlot + 32768))[qw] = mrow;
            ((float*)(mySlot + 33280))[qw] = lrow;
        }
    }
    __threadfence();                               // release: partial visible device-wide
    __syncthreads();
    if (tid == 0) oldFlag = atomicAdd(&flags[pairIdx], 1);
    __syncthreads();
    if (oldFlag == 0) return;                      // first arriver: partner will merge
    __threadfence();                               // acquire: partner's partial visible

    const char* pSlot = partials + (size_t)(pairIdx*2 + (ks ^ 1)) * SLOT;
    const unsigned short* pacc = (const unsigned short*)pSlot;
    float mp = ((const float*)(pSlot + 32768))[qw];
    float lp = ((const float*)(pSlot + 33280))[qw];
    float nm = fmaxf(mrow, mp);
    float ssf = exp2f(mrow - nm);
    float spf = exp2f(mp   - nm);
    float lm  = lrow*ssf + lp*spf;
    float invl = 1.0f / lm;
    #pragma unroll
    for (int dt = 0; dt < 4; ++dt)
        #pragma unroll
        for (int qd = 0; qd < 4; ++qd) {
            u16x4 pp = *(const u16x4*)&pacc[qw*128 + dt*32 + qd*8 + hi*4];
            u16x4 o4;
            #pragma unroll
            for (int j = 0; j < 4; ++j) {
                // both sides bf16-rounded -> result independent of arrival order
                float v = bf2f(f2bf(acc[dt][qd*4 + j]))*ssf + bf2f(pp[j])*spf;
                o4[j] = f2bf(v * invl);
            }
            *(u16x4*)&attn_out[(size_t)(b*SEQ + qg)*DIMX + h*HD + dt*32 + qd*8 + hi*4] = o4;
        }
}

extern "C" void kernel_launch(void* const* d_in, const int* in_sizes, int n_in,
                              void* d_out, int out_size, void* d_ws, size_t ws_size,
                              hipStream_t stream) {
    const float* x  = (const float*)d_in[0];
    const float* Wq = (const float*)d_in[1];
    const float* Wk = (const float*)d_in[2];
    const float* Wv = (const float*)d_in[3];
    const float* Wo = (const float*)d_in[4];

    // ws layout (all u16), total 92.3 MB
    unsigned short* xb   = (unsigned short*)d_ws;                 // 4096x2048
    unsigned short* Wtq  = xb  + (size_t)MTOK*DIMX;               // 4096x2048 (QKV weights, NxK)
    unsigned short* Wto  = Wtq + (size_t)NQKV*DIMX;               // 2048x2048 (Wo^T)
    unsigned short* qkv  = Wto + (size_t)DIMX*DIMX;               // 4096x3072 (Q|K, ld 3072)
    unsigned short* aout = qkv + (size_t)MTOK*QKLD;               // 4096x2048
    unsigned short* Vt   = aout + (size_t)MTOK*DIMX;              // [2][8][128][2048]
    // attn split-KV scratch in regions dead after GEMM1 (xb + front of Wtq):
    char* partials = (char*)xb;                                   // 512 slots x 33792B = 17.3MB
    int*  flags    = (int*)Wto - 256;                             // last 1KB of Wtq region

    k_convert<<<(MTOK*DIMX/8 + 255)/256, 256, 0, stream>>>(x, xb, MTOK*DIMX/8);

    dim3 tg32(DIMX/64, DIMX/64);
    dim3 tg16(1024/64, DIMX/64);
    k_transpose<<<tg32, 256, 0, stream>>>(Wq, Wtq,                         DIMX, DIMX);
    k_transpose<<<tg16, 256, 0, stream>>>(Wk, Wtq + (size_t)2048*DIMX,     DIMX, 1024);
    k_transpose<<<tg16, 256, 0, stream>>>(Wv, Wtq + (size_t)3072*DIMX,     DIMX, 1024);
    k_transpose<<<tg32, 256, 0, stream>>>(Wo, Wto,                         DIMX, DIMX);

    // GEMM1: 4096x4096x2048, 256x256 tiles -> 256 blocks
    k_gemm256<4, 0><<<256, 512, 0, stream>>>(xb, Wtq, qkv, Vt, MTOK, NQKV, DIMX, QKLD);

    k_rope<<<(MTOK*(NH+NKV)*64)/256, 256, 0, stream>>>(qkv);

    hipMemsetAsync(flags, 0, 256 * sizeof(int), stream);
    k_attn<<<768, 256, 0, stream>>>(qkv, Vt, aout, partials, flags);

    // GEMM2: 4096x2048x2048, 256x128 tiles -> 256 blocks
    k_gemm256<2, 1><<<256, 512, 0, stream>>>(aout, Wto, (float*)d_out, nullptr, MTOK, DIMX, DIMX, DIMX);
}

// Round 16
// 213.194 us; speedup vs baseline: 1.5382x; 1.5382x over previous
//
#include <hip/hip_runtime.h>

// Problem constants
#define DIMX 2048
#define SEQ  2048
#define BATCH 2
#define NH   16
#define NKV  8
#define HD   128
#define MTOK (BATCH*SEQ)   // 4096 tokens
#define NQKV 4096          // GEMM1 output cols: 2048 Q + 1024 K + 1024 V
#define QKLD 3072          // qkv buffer stride (Q+K only; V goes to Vt)

typedef __bf16 bf16x8 __attribute__((ext_vector_type(8)));
typedef float  f32x4  __attribute__((ext_vector_type(4)));
typedef float  f32x16 __attribute__((ext_vector_type(16)));
typedef unsigned short u16x8 __attribute__((ext_vector_type(8)));
typedef unsigned short u16x4 __attribute__((ext_vector_type(4)));
typedef unsigned int   u32x4 __attribute__((ext_vector_type(4)));

__device__ __forceinline__ unsigned short f2bf(float f) {
    unsigned u = __builtin_bit_cast(unsigned, f);
    u += 0x7fffu + ((u >> 16) & 1u);            // RNE
    return (unsigned short)(u >> 16);
}
__device__ __forceinline__ float bf2f(unsigned short h) {
    unsigned u = ((unsigned)h) << 16;
    return __builtin_bit_cast(float, u);
}

__device__ __forceinline__ void gload16(const void* g, void* l) {
    __builtin_amdgcn_global_load_lds(
        (const __attribute__((address_space(1))) unsigned int*)g,
        (__attribute__((address_space(3))) unsigned int*)l, 16, 0, 0);
}

// ---------------- fp32 -> bf16 elementwise convert (8 elems/thread) ----------------
__global__ __launch_bounds__(256) void k_convert(const float* __restrict__ in,
                                                 unsigned short* __restrict__ out, int n8) {
    int i = blockIdx.x * 256 + threadIdx.x;
    if (i >= n8) return;
    f32x4 a = ((const f32x4*)in)[(size_t)i*2];
    f32x4 b = ((const f32x4*)in)[(size_t)i*2+1];
    u16x8 o;
    o[0]=f2bf(a[0]); o[1]=f2bf(a[1]); o[2]=f2bf(a[2]); o[3]=f2bf(a[3]);
    o[4]=f2bf(b[0]); o[5]=f2bf(b[1]); o[6]=f2bf(b[2]); o[7]=f2bf(b[3]);
    ((u16x8*)out)[i] = o;
}

// ---------------- fp32 KxN -> bf16 NxK transpose (64x64 tiles via LDS) ----------------
__global__ __launch_bounds__(256) void k_transpose(const float* __restrict__ W,
                                                   unsigned short* __restrict__ Wt,
                                                   int K, int N) {
    __shared__ unsigned short tile[64*65];
    int t = threadIdx.x;
    int n0 = blockIdx.x * 64, k0 = blockIdx.y * 64;
    #pragma unroll
    for (int i = 0; i < 16; ++i) {
        int idx = t + i*256, r = idx >> 6, c = idx & 63;
        tile[r*65+c] = f2bf(W[(size_t)(k0+r)*N + n0 + c]);
    }
    __syncthreads();
    #pragma unroll
    for (int i = 0; i < 16; ++i) {
        int idx = t + i*256, n = idx >> 6, k = idx & 63;
        Wt[(size_t)(n0+n)*K + k0 + k] = tile[k*65+n];
    }
}

// ---------------- 256-wide bf16 GEMM: BMx(NREP*64) tile, BK=64, 8 waves (2Mx4N) ----------------
template<int NREP, int MODE>
__global__ __launch_bounds__(512, 2) void k_gemm256(const unsigned short* __restrict__ A,
                                                    const unsigned short* __restrict__ Bt,
                                                    void* __restrict__ Cv,
                                                    unsigned short* __restrict__ Vt,
                                                    int M, int N, int K, int ldc) {
    constexpr int BN  = NREP * 64;     // 256 or 128
    constexpr int BWC = NREP * 16;     // per-wave col span
    __shared__ __align__(16) char As[2][32768];
    __shared__ __align__(16) char Bs[2][BN * 128];
    int bid = blockIdx.x;
    int rem = (bid & 7) * 32 + (bid >> 3);      // T1 bijective XCD swizzle (nwg=256)
    int bx = rem & 15, by = rem >> 4;
    int row0 = by * 256, col0 = bx * BN;
    int tid = threadIdx.x, wave = tid >> 6, lane = tid & 63;
    int wr = wave >> 2, wc = wave & 3;
    int g = lane >> 4, r16 = lane & 15;
    const char* Ab = (const char*)A;
    const char* Bb = (const char*)Bt;

    f32x4 acc[8][NREP] = {};

    auto STAGE = [&](int buf, int t) {
        int k0b = t * 128;                       // byte offset into K (64 elems * 2B)
        #pragma unroll
        for (int p = 0; p < 4; ++p) {
            int c = wave * 4 + p;
            int o = c * 1024 + lane * 16;
            int row = o >> 7;
            int colb = (o & 127) ^ ((row & 7) << 4);
            gload16(Ab + (size_t)(row0 + row) * (size_t)(K * 2) + k0b + colb, &As[buf][c * 1024]);
        }
        #pragma unroll
        for (int p = 0; p < NREP; ++p) {
            int c = wave * NREP + p;
            int o = c * 1024 + lane * 16;
            int row = o >> 7;
            int colb = (o & 127) ^ ((row & 7) << 4);
            gload16(Bb + (size_t)(col0 + row) * (size_t)(K * 2) + k0b + colb, &Bs[buf][c * 1024]);
        }
    };

    int nt = K >> 6;
    STAGE(0, 0);
    STAGE(1, 1);
    if constexpr (NREP == 4) asm volatile("s_waitcnt vmcnt(8)" ::: "memory");
    else                     asm volatile("s_waitcnt vmcnt(6)" ::: "memory");
    __builtin_amdgcn_s_barrier();

    for (int t = 0; t < nt; ++t) {
        int buf = t & 1;
        const char* AL = As[buf];
        const char* BL = Bs[buf];
        bf16x8 a0[4][2], a1[4][2], bfr[NREP][2];
        #pragma unroll
        for (int mi = 0; mi < 4; ++mi)
            #pragma unroll
            for (int s = 0; s < 2; ++s) {
                int r = wr*128 + mi*16 + r16;
                int o = r*128 + s*64 + g*16;
                a0[mi][s] = *(const bf16x8*)(AL + (o ^ ((r & 7) << 4)));
            }
        #pragma unroll
        for (int ni = 0; ni < NREP; ++ni)
            #pragma unroll
            for (int s = 0; s < 2; ++s) {
                int r = wc*BWC + ni*16 + r16;
                int o = r*128 + s*64 + g*16;
                bfr[ni][s] = *(const bf16x8*)(BL + (o ^ ((r & 7) << 4)));
            }
        __builtin_amdgcn_s_setprio(1);
        #pragma unroll
        for (int mi = 0; mi < 4; ++mi)
            #pragma unroll
            for (int ni = 0; ni < NREP; ++ni)
                #pragma unroll
                for (int s = 0; s < 2; ++s)
                    acc[mi][ni] = __builtin_amdgcn_mfma_f32_16x16x32_bf16(a0[mi][s], bfr[ni][s], acc[mi][ni], 0, 0, 0);
        __builtin_amdgcn_s_setprio(0);
        #pragma unroll
        for (int mi = 0; mi < 4; ++mi)
            #pragma unroll
            for (int s = 0; s < 2; ++s) {
                int r = wr*128 + 64 + mi*16 + r16;
                int o = r*128 + s*64 + g*16;
                a1[mi][s] = *(const bf16x8*)(AL + (o ^ ((r & 7) << 4)));
            }
        asm volatile("s_waitcnt lgkmcnt(0)" ::: "memory");
        __builtin_amdgcn_sched_barrier(0);
        __builtin_amdgcn_s_barrier();            // barrier A: block-wide done reading buf
        if (t + 2 < nt) STAGE(buf, t + 2);       // overwrite freed buffer (loads fly under MFMA)
        __builtin_amdgcn_sched_barrier(0);
        __builtin_amdgcn_s_setprio(1);
        #pragma unroll
        for (int mi = 0; mi < 4; ++mi)
            #pragma unroll
            for (int ni = 0; ni < NREP; ++ni)
                #pragma unroll
                for (int s = 0; s < 2; ++s)
                    acc[mi+4][ni] = __builtin_amdgcn_mfma_f32_16x16x32_bf16(a1[mi][s], bfr[ni][s], acc[mi+4][ni], 0, 0, 0);
        __builtin_amdgcn_s_setprio(0);
        if (t + 2 < nt) {
            if constexpr (NREP == 4) asm volatile("s_waitcnt vmcnt(8)" ::: "memory");
            else                     asm volatile("s_waitcnt vmcnt(6)" ::: "memory");
        } else {
            asm volatile("s_waitcnt vmcnt(0)" ::: "memory");
        }
        __builtin_amdgcn_s_barrier();            // barrier B: K-tile t+1 data landed everywhere
    }

    // epilogue
    #pragma unroll
    for (int mi = 0; mi < 8; ++mi)
        #pragma unroll
        for (int ni = 0; ni < NREP; ++ni) {
            if (MODE == 0 && col0 >= 3072) {
                int vcol = col0 + wc*BWC + ni*16 + r16 - 3072;
                int d = vcol & 127, kh = vcol >> 7;
                int row = row0 + wr*128 + mi*16 + g*4;
                int b = row >> 11, s = row & (SEQ-1);
                u16x4 pk;
                #pragma unroll
                for (int rr = 0; rr < 4; ++rr) pk[rr] = f2bf(acc[mi][ni][rr]);
                *(u16x4*)&Vt[((size_t)(b*NKV + kh)*HD + d)*SEQ + s] = pk;
            } else {
                #pragma unroll
                for (int rr = 0; rr < 4; ++rr) {
                    int row = row0 + wr*128 + mi*16 + g*4 + rr;
                    int col = col0 + wc*BWC + ni*16 + r16;
                    float v = acc[mi][ni][rr];
                    if (MODE == 1) ((float*)Cv)[(size_t)row*ldc + col] = v;
                    else ((unsigned short*)Cv)[(size_t)row*ldc + col] = f2bf(v);
                }
            }
        }
}

// ---------------- RoPE in place (x4 vectorized); Q pre-scaled by rsqrt(128)*log2(e) ----------------
// Thread handles 4 rotation pairs (i4..i4+3, partners at +64) via u16x4 loads/stores.
__global__ __launch_bounds__(256) void k_rope(unsigned short* __restrict__ qkv) {
    int tid = blockIdx.x * 256 + threadIdx.x;   // MTOK*(NH+NKV)*16 threads
    int i4   = (tid & 15) * 4;                  // first rotation-pair index of this thread
    int rest = tid >> 4;
    int head = rest % (NH + NKV);
    int tok  = rest / (NH + NKV);
    int pos  = tok & (SEQ - 1);
    size_t base = (size_t)tok * QKLD + head*HD;
    u16x4 a = *(const u16x4*)&qkv[base + i4];
    u16x4 c4 = *(const u16x4*)&qkv[base + i4 + 64];
    float sc = (head < NH) ? 0.12754984523341717f : 1.0f;  // rsqrt(128)*log2(e) folded into Q
    u16x4 oa, ob;
    #pragma unroll
    for (int j = 0; j < 4; ++j) {
        int i = i4 + j;
        float x1 = bf2f(a[j]);
        float x2 = bf2f(c4[j]);
        float inv = exp2f(-0.20762050593046014f * (float)i);   // 10000^(-i/64)
        float ang = (float)pos * inv;
        float s, c;
        sincosf(ang, &s, &c);
        oa[j] = f2bf((x1*c - x2*s) * sc);
        ob[j] = f2bf((x2*c + x1*s) * sc);
    }
    *(u16x4*)&qkv[base + i4]      = oa;
    *(u16x4*)&qkv[base + i4 + 64] = ob;
}

// ---------------- causal GQA flash attention v6 (one chunk per block) — validated R10/R14 ----------------
// 512 blocks x 256 thr (4 waves), 2 blocks/CU (LDS 64KB x 2 = 128KB <= 160KB).
// Decode: half=bid>>8, rem=bid&255, xcd=rem&7, idx=rem>>3, bh=xcd*4+(idx>>3) in [0,32),
// p=idx&7, qt = half ? 15-p : p. Blocks bid and bid+256 share (bh,p) with complementary qt.
// R14/R15 lesson: this kernel is WORK-throughput-bound (8704 tiles x 2.24us/tile/CU-pair),
// not makespan-bound; split-KV and occupancy tricks regress. Per-tile serial chain is the
// structural cost at 2 waves/SIMD.
__global__ __launch_bounds__(256, 2) void k_attn(const unsigned short* __restrict__ qkv,
                                                 const unsigned short* __restrict__ Vt,
                                                 unsigned short* __restrict__ attn_out) {
    __shared__ __align__(16) char KVs[2][32768];   // [buf]: K [64][128] @256B rows | V [128][64] @128B rows
    int bid = blockIdx.x;
    int half = bid >> 8;
    int rem  = bid & 255;
    int xcd = rem & 7, idx = rem >> 3;             // 32 slots per XCD per half
    int bh  = xcd * 4 + (idx >> 3);                // [0,32): 4 bh per XCD (L2 locality)
    int p   = idx & 7;
    int qt  = half ? (15 - p) : p;                 // complementary across the two halves
    int b = bh >> 4, h = bh & 15, kvh = h >> 1;
    int tid = threadIdx.x, wave = tid >> 6, lane = tid & 63;
    int l31 = lane & 31, hi = lane >> 5;
    int nt = 2*qt + 2;                             // kv-tiles for this chunk
    int q0w = qt*128 + wave*32;
    int qg  = q0w + l31;
    const unsigned short* qbase = qkv + (size_t)(b*SEQ)*QKLD;
    const char* kbase = (const char*)(qbase + DIMX + kvh*HD);                    // + row*QKLD*2
    const char* vbase = (const char*)(Vt + ((size_t)(b*NKV + kvh)*HD)*SEQ);      // + d*SEQ*2

    bf16x8 qf[8];
    {
        const unsigned short* qr = qbase + (size_t)qg*QKLD + h*HD;
        #pragma unroll
        for (int s2 = 0; s2 < 8; ++s2) qf[s2] = *(const bf16x8*)(qr + s2*16 + hi*8);
    }

    f32x16 acc[4] = {};                            // O^T: d = 32dt + (r&3)+8(r>>2)+4hi, q = l31
    float mrow = -1e30f, lrow = 0.f;

    auto STAGE = [&](int v, int buf) {
        int kv0 = v * 64;
        char* KL = KVs[buf];
        char* VL = KL + 16384;
        #pragma unroll
        for (int pp = 0; pp < 4; ++pp) {
            int c = wave*4 + pp;
            int row  = c*4 + (lane >> 4);
            int colb = ((lane & 15) * 16) ^ ((row & 7) << 4);
            gload16(kbase + (size_t)(kv0 + row)*(QKLD*2) + colb, KL + c*1024);
            int d    = c*8 + (lane >> 3);
            int colv = ((lane & 7) * 16) ^ ((d & 7) << 4);
            gload16(vbase + (size_t)d*(SEQ*2) + (size_t)kv0*2 + colv, VL + c*1024);
        }
    };

    STAGE(0, 0);
    asm volatile("s_waitcnt vmcnt(0)" ::: "memory");
    __syncthreads();

    for (int v = 0; v < nt; ++v) {
        int buf = v & 1;
        int kv0 = v * 64;
        if (v + 1 < nt) STAGE(v + 1, buf ^ 1);      // loads fly under this tile's compute
        const char* KL = KVs[buf];
        const char* VL = KL + 16384;
        if (kv0 <= q0w + 31) {
            f32x16 st0 = {}, st1 = {};
            const char* kr0 = KL + l31*256;
            const char* kr1 = KL + (32 + l31)*256;
            unsigned sw = (unsigned)((l31 & 7) << 4);
            __builtin_amdgcn_s_setprio(1);
            #pragma unroll
            for (int s2 = 0; s2 < 8; ++s2) {
                unsigned off = (unsigned)(s2*32 + hi*16);
                bf16x8 kf0 = *(const bf16x8*)(kr0 + (off ^ sw));
                bf16x8 kf1 = *(const bf16x8*)(kr1 + (off ^ sw));
                st0 = __builtin_amdgcn_mfma_f32_32x32x16_bf16(kf0, qf[s2], st0, 0, 0, 0);
                st1 = __builtin_amdgcn_mfma_f32_32x32x16_bf16(kf1, qf[s2], st1, 0, 0, 0);
            }
            __builtin_amdgcn_s_setprio(0);
            if (kv0 + 63 > q0w) {
                #pragma unroll
                for (int r = 0; r < 16; ++r) {
                    int kvr = kv0 + (r & 3) + 8*(r >> 2) + 4*hi;
                    st0[r] = (kvr      <= qg) ? st0[r] : -1e30f;
                    st1[r] = (kvr + 32 <= qg) ? st1[r] : -1e30f;
                }
            }
            float mt = -1e30f;
            #pragma unroll
            for (int r = 0; r < 16; ++r) { mt = fmaxf(mt, st0[r]); mt = fmaxf(mt, st1[r]); }
            mt = fmaxf(mt, __shfl_xor(mt, 32, 64));
            if (!__all(mt - mrow <= 8.0f)) {
                float mn = fmaxf(mrow, mt);
                float corr = exp2f(mrow - mn);
                mrow = mn; lrow *= corr;
                #pragma unroll
                for (int dt = 0; dt < 4; ++dt)
                    #pragma unroll
                    for (int r = 0; r < 16; ++r) acc[dt][r] *= corr;
            }
            float rs = 0.f;
            #pragma unroll
            for (int r = 0; r < 16; ++r) {
                float p0 = exp2f(st0[r] - mrow); st0[r] = p0; rs += p0;
                float p1 = exp2f(st1[r] - mrow); st1[r] = p1; rs += p1;
            }
            lrow += rs + __shfl_xor(rs, 32, 64);
            #pragma unroll
            for (int t = 0; t < 2; ++t)
                #pragma unroll
                for (int ks = 0; ks < 2; ++ks) {
                    const f32x16& stt = t ? st1 : st0;
                    int rb = ks * 8;
                    float p0 = stt[rb+0], p1 = stt[rb+1], p2 = stt[rb+2], p3 = stt[rb+3];
                    float p4 = stt[rb+4], p5 = stt[rb+5], p6 = stt[rb+6], p7 = stt[rb+7];
                    unsigned w0, w1, w2, w3;
                    asm("v_cvt_pk_bf16_f32 %0, %1, %2" : "=v"(w0) : "v"(p0), "v"(p1));
                    asm("v_cvt_pk_bf16_f32 %0, %1, %2" : "=v"(w1) : "v"(p2), "v"(p3));
                    asm("v_cvt_pk_bf16_f32 %0, %1, %2" : "=v"(w2) : "v"(p4), "v"(p5));
                    asm("v_cvt_pk_bf16_f32 %0, %1, %2" : "=v"(w3) : "v"(p6), "v"(p7));
                    asm("v_permlane32_swap_b32 %0, %1" : "+v"(w0), "+v"(w2));
                    asm("v_permlane32_swap_b32 %0, %1" : "+v"(w1), "+v"(w3));
                    u32x4 pu = {w0, w1, w2, w3};
                    bf16x8 pfrag = __builtin_bit_cast(bf16x8, pu);
                    int ks4 = t*2 + ks;
                    __builtin_amdgcn_s_setprio(1);
                    #pragma unroll
                    for (int dt = 0; dt < 4; ++dt) {
                        int d = dt*32 + l31;
                        bf16x8 vf = *(const bf16x8*)(VL + d*128 +
                                     (((unsigned)(ks4*32 + hi*16)) ^ ((unsigned)((d & 7) << 4))));
                        acc[dt] = __builtin_amdgcn_mfma_f32_32x32x16_bf16(vf, pfrag, acc[dt], 0, 0, 0);
                    }
                    __builtin_amdgcn_s_setprio(0);
                }
        }
        asm volatile("s_waitcnt vmcnt(0)" ::: "memory");   // next tile landed block-wide
        __syncthreads();
    }

    // ---- epilogue: normalize (lane-local), write bf16, 8B stores ----
    float inv = 1.0f / lrow;
    #pragma unroll
    for (int dt = 0; dt < 4; ++dt)
        #pragma unroll
        for (int qd = 0; qd < 4; ++qd) {
            u16x4 o4;
            #pragma unroll
            for (int j = 0; j < 4; ++j) o4[j] = f2bf(acc[dt][qd*4 + j] * inv);
            *(u16x4*)&attn_out[(size_t)(b*SEQ + qg)*DIMX + h*HD + dt*32 + qd*8 + hi*4] = o4;
        }
}

extern "C" void kernel_launch(void* const* d_in, const int* in_sizes, int n_in,
                              void* d_out, int out_size, void* d_ws, size_t ws_size,
                              hipStream_t stream) {
    const float* x  = (const float*)d_in[0];
    const float* Wq = (const float*)d_in[1];
    const float* Wk = (const float*)d_in[2];
    const float* Wv = (const float*)d_in[3];
    const float* Wo = (const float*)d_in[4];

    // ws layout (all u16), total 92.3 MB
    unsigned short* xb   = (unsigned short*)d_ws;                 // 4096x2048
    unsigned short* Wtq  = xb  + (size_t)MTOK*DIMX;               // 4096x2048 (QKV weights, NxK)
    unsigned short* Wto  = Wtq + (size_t)NQKV*DIMX;               // 2048x2048 (Wo^T)
    unsigned short* qkv  = Wto + (size_t)DIMX*DIMX;               // 4096x3072 (Q|K, ld 3072)
    unsigned short* aout = qkv + (size_t)MTOK*QKLD;               // 4096x2048
    unsigned short* Vt   = aout + (size_t)MTOK*DIMX;              // [2][8][128][2048]

    k_convert<<<(MTOK*DIMX/8 + 255)/256, 256, 0, stream>>>(x, xb, MTOK*DIMX/8);

    dim3 tg32(DIMX/64, DIMX/64);
    dim3 tg16(1024/64, DIMX/64);
    k_transpose<<<tg32, 256, 0, stream>>>(Wq, Wtq,                         DIMX, DIMX);
    k_transpose<<<tg16, 256, 0, stream>>>(Wk, Wtq + (size_t)2048*DIMX,     DIMX, 1024);
    k_transpose<<<tg16, 256, 0, stream>>>(Wv, Wtq + (size_t)3072*DIMX,     DIMX, 1024);
    k_transpose<<<tg32, 256, 0, stream>>>(Wo, Wto,                         DIMX, DIMX);

    // GEMM1: 4096x4096x2048, 256x256 tiles -> 256 blocks
    k_gemm256<4, 0><<<256, 512, 0, stream>>>(xb, Wtq, qkv, Vt, MTOK, NQKV, DIMX, QKLD);

    k_rope<<<(MTOK*(NH+NKV)*16)/256, 256, 0, stream>>>(qkv);

    k_attn<<<512, 256, 0, stream>>>(qkv, Vt, aout);

    // GEMM2: 4096x2048x2048, 256x128 tiles -> 256 blocks
    k_gemm256<2, 1><<<256, 512, 0, stream>>>(aout, Wto, (float*)d_out, nullptr, MTOK, DIMX, DIMX, DIMX);
}

// Round 17
// 208.415 us; speedup vs baseline: 1.5735x; 1.0229x over previous
//
#include <hip/hip_runtime.h>

// Problem constants
#define DIMX 2048
#define SEQ  2048
#define BATCH 2
#define NH   16
#define NKV  8
#define HD   128
#define MTOK (BATCH*SEQ)   // 4096 tokens
#define NQKV 4096          // GEMM1 output cols: 2048 Q + 1024 K + 1024 V
#define QKLD 3072          // qkv buffer stride (Q+K only; V goes to Vt)

typedef __bf16 bf16x8 __attribute__((ext_vector_type(8)));
typedef float  f32x4  __attribute__((ext_vector_type(4)));
typedef float  f32x16 __attribute__((ext_vector_type(16)));
typedef unsigned short u16x8 __attribute__((ext_vector_type(8)));
typedef unsigned short u16x4 __attribute__((ext_vector_type(4)));
typedef unsigned int   u32x4 __attribute__((ext_vector_type(4)));

__device__ __forceinline__ unsigned short f2bf(float f) {
    unsigned u = __builtin_bit_cast(unsigned, f);
    u += 0x7fffu + ((u >> 16) & 1u);            // RNE
    return (unsigned short)(u >> 16);
}
__device__ __forceinline__ float bf2f(unsigned short h) {
    unsigned u = ((unsigned)h) << 16;
    return __builtin_bit_cast(float, u);
}

__device__ __forceinline__ void gload16(const void* g, void* l) {
    __builtin_amdgcn_global_load_lds(
        (const __attribute__((address_space(1))) unsigned int*)g,
        (__attribute__((address_space(3))) unsigned int*)l, 16, 0, 0);
}

// ---------------- fp32 -> bf16 elementwise convert (8 elems/thread) ----------------
__global__ __launch_bounds__(256) void k_convert(const float* __restrict__ in,
                                                 unsigned short* __restrict__ out, int n8) {
    int i = blockIdx.x * 256 + threadIdx.x;
    if (i >= n8) return;
    f32x4 a = ((const f32x4*)in)[(size_t)i*2];
    f32x4 b = ((const f32x4*)in)[(size_t)i*2+1];
    u16x8 o;
    o[0]=f2bf(a[0]); o[1]=f2bf(a[1]); o[2]=f2bf(a[2]); o[3]=f2bf(a[3]);
    o[4]=f2bf(b[0]); o[5]=f2bf(b[1]); o[6]=f2bf(b[2]); o[7]=f2bf(b[3]);
    ((u16x8*)out)[i] = o;
}

// ---------------- merged fp32 KxN -> bf16 NxK transpose for all 4 weights ----------------
// One launch, 3072 blocks: [0,1024) Wq, [1024,1536) Wk, [1536,2048) Wv, [2048,3072) Wo.
// 64x64 tiles; float4 global loads (16B/lane), u16x4 stores (8B/lane).
__global__ __launch_bounds__(256) void k_transpose_all(const float* __restrict__ Wq,
                                                       const float* __restrict__ Wk,
                                                       const float* __restrict__ Wv,
                                                       const float* __restrict__ Wo,
                                                       unsigned short* __restrict__ Wtq,
                                                       unsigned short* __restrict__ Wto) {
    __shared__ unsigned short tile[64*65];
    int bid = blockIdx.x;
    const float* W; unsigned short* Wt; int N, n0, k0;
    if (bid < 1024)      { W = Wq; Wt = Wtq;                       N = 2048; int s = bid;        n0 = (s & 31)*64; k0 = (s >> 5)*64; }
    else if (bid < 1536) { W = Wk; Wt = Wtq + (size_t)2048*DIMX;   N = 1024; int s = bid - 1024; n0 = (s & 15)*64; k0 = (s >> 4)*64; }
    else if (bid < 2048) { W = Wv; Wt = Wtq + (size_t)3072*DIMX;   N = 1024; int s = bid - 1536; n0 = (s & 15)*64; k0 = (s >> 4)*64; }
    else                 { W = Wo; Wt = Wto;                       N = 2048; int s = bid - 2048; n0 = (s & 31)*64; k0 = (s >> 5)*64; }
    int t = threadIdx.x;
    #pragma unroll
    for (int i = 0; i < 4; ++i) {
        int idx = t + i*256;                 // 1024 float4 slots = 64 rows x 16
        int r = idx >> 4, c4 = (idx & 15)*4;
        f32x4 v = *(const f32x4*)&W[(size_t)(k0 + r)*N + n0 + c4];
        tile[r*65 + c4 + 0] = f2bf(v[0]);
        tile[r*65 + c4 + 1] = f2bf(v[1]);
        tile[r*65 + c4 + 2] = f2bf(v[2]);
        tile[r*65 + c4 + 3] = f2bf(v[3]);
    }
    __syncthreads();
    #pragma unroll
    for (int i = 0; i < 4; ++i) {
        int idx = t + i*256;                 // 1024 u16x4 slots = 64 n-rows x 16
        int n = idx >> 4, k4 = (idx & 15)*4;
        u16x4 o4;
        #pragma unroll
        for (int j = 0; j < 4; ++j) o4[j] = tile[(k4 + j)*65 + n];
        *(u16x4*)&Wt[(size_t)(n0 + n)*DIMX + k0 + k4] = o4;
    }
}

// ---------------- 256-wide bf16 GEMM: BMx(NREP*64) tile, BK=64, 8 waves (2Mx4N) ----------------
template<int NREP, int MODE>
__global__ __launch_bounds__(512, 2) void k_gemm256(const unsigned short* __restrict__ A,
                                                    const unsigned short* __restrict__ Bt,
                                                    void* __restrict__ Cv,
                                                    unsigned short* __restrict__ Vt,
                                                    int M, int N, int K, int ldc) {
    constexpr int BN  = NREP * 64;     // 256 or 128
    constexpr int BWC = NREP * 16;     // per-wave col span
    __shared__ __align__(16) char As[2][32768];
    __shared__ __align__(16) char Bs[2][BN * 128];
    int bid = blockIdx.x;
    int rem = (bid & 7) * 32 + (bid >> 3);      // T1 bijective XCD swizzle (nwg=256)
    int bx = rem & 15, by = rem >> 4;
    int row0 = by * 256, col0 = bx * BN;
    int tid = threadIdx.x, wave = tid >> 6, lane = tid & 63;
    int wr = wave >> 2, wc = wave & 3;
    int g = lane >> 4, r16 = lane & 15;
    const char* Ab = (const char*)A;
    const char* Bb = (const char*)Bt;

    f32x4 acc[8][NREP] = {};

    auto STAGE = [&](int buf, int t) {
        int k0b = t * 128;                       // byte offset into K (64 elems * 2B)
        #pragma unroll
        for (int p = 0; p < 4; ++p) {
            int c = wave * 4 + p;
            int o = c * 1024 + lane * 16;
            int row = o >> 7;
            int colb = (o & 127) ^ ((row & 7) << 4);
            gload16(Ab + (size_t)(row0 + row) * (size_t)(K * 2) + k0b + colb, &As[buf][c * 1024]);
        }
        #pragma unroll
        for (int p = 0; p < NREP; ++p) {
            int c = wave * NREP + p;
            int o = c * 1024 + lane * 16;
            int row = o >> 7;
            int colb = (o & 127) ^ ((row & 7) << 4);
            gload16(Bb + (size_t)(col0 + row) * (size_t)(K * 2) + k0b + colb, &Bs[buf][c * 1024]);
        }
    };

    int nt = K >> 6;
    STAGE(0, 0);
    STAGE(1, 1);
    if constexpr (NREP == 4) asm volatile("s_waitcnt vmcnt(8)" ::: "memory");
    else                     asm volatile("s_waitcnt vmcnt(6)" ::: "memory");
    __builtin_amdgcn_s_barrier();

    for (int t = 0; t < nt; ++t) {
        int buf = t & 1;
        const char* AL = As[buf];
        const char* BL = Bs[buf];
        bf16x8 a0[4][2], a1[4][2], bfr[NREP][2];
        #pragma unroll
        for (int mi = 0; mi < 4; ++mi)
            #pragma unroll
            for (int s = 0; s < 2; ++s) {
                int r = wr*128 + mi*16 + r16;
                int o = r*128 + s*64 + g*16;
                a0[mi][s] = *(const bf16x8*)(AL + (o ^ ((r & 7) << 4)));
            }
        #pragma unroll
        for (int ni = 0; ni < NREP; ++ni)
            #pragma unroll
            for (int s = 0; s < 2; ++s) {
                int r = wc*BWC + ni*16 + r16;
                int o = r*128 + s*64 + g*16;
                bfr[ni][s] = *(const bf16x8*)(BL + (o ^ ((r & 7) << 4)));
            }
        __builtin_amdgcn_s_setprio(1);
        #pragma unroll
        for (int mi = 0; mi < 4; ++mi)
            #pragma unroll
            for (int ni = 0; ni < NREP; ++ni)
                #pragma unroll
                for (int s = 0; s < 2; ++s)
                    acc[mi][ni] = __builtin_amdgcn_mfma_f32_16x16x32_bf16(a0[mi][s], bfr[ni][s], acc[mi][ni], 0, 0, 0);
        __builtin_amdgcn_s_setprio(0);
        #pragma unroll
        for (int mi = 0; mi < 4; ++mi)
            #pragma unroll
            for (int s = 0; s < 2; ++s) {
                int r = wr*128 + 64 + mi*16 + r16;
                int o = r*128 + s*64 + g*16;
                a1[mi][s] = *(const bf16x8*)(AL + (o ^ ((r & 7) << 4)));
            }
        asm volatile("s_waitcnt lgkmcnt(0)" ::: "memory");
        __builtin_amdgcn_sched_barrier(0);
        __builtin_amdgcn_s_barrier();            // barrier A: block-wide done reading buf
        if (t + 2 < nt) STAGE(buf, t + 2);       // overwrite freed buffer (loads fly under MFMA)
        __builtin_amdgcn_sched_barrier(0);
        __builtin_amdgcn_s_setprio(1);
        #pragma unroll
        for (int mi = 0; mi < 4; ++mi)
            #pragma unroll
            for (int ni = 0; ni < NREP; ++ni)
                #pragma unroll
                for (int s = 0; s < 2; ++s)
                    acc[mi+4][ni] = __builtin_amdgcn_mfma_f32_16x16x32_bf16(a1[mi][s], bfr[ni][s], acc[mi+4][ni], 0, 0, 0);
        __builtin_amdgcn_s_setprio(0);
        if (t + 2 < nt) {
            if constexpr (NREP == 4) asm volatile("s_waitcnt vmcnt(8)" ::: "memory");
            else                     asm volatile("s_waitcnt vmcnt(6)" ::: "memory");
        } else {
            asm volatile("s_waitcnt vmcnt(0)" ::: "memory");
        }
        __builtin_amdgcn_s_barrier();            // barrier B: K-tile t+1 data landed everywhere
    }

    // epilogue
    #pragma unroll
    for (int mi = 0; mi < 8; ++mi)
        #pragma unroll
        for (int ni = 0; ni < NREP; ++ni) {
            if (MODE == 0 && col0 >= 3072) {
                int vcol = col0 + wc*BWC + ni*16 + r16 - 3072;
                int d = vcol & 127, kh = vcol >> 7;
                int row = row0 + wr*128 + mi*16 + g*4;
                int b = row >> 11, s = row & (SEQ-1);
                u16x4 pk;
                #pragma unroll
                for (int rr = 0; rr < 4; ++rr) pk[rr] = f2bf(acc[mi][ni][rr]);
                *(u16x4*)&Vt[((size_t)(b*NKV + kh)*HD + d)*SEQ + s] = pk;
            } else {
                #pragma unroll
                for (int rr = 0; rr < 4; ++rr) {
                    int row = row0 + wr*128 + mi*16 + g*4 + rr;
                    int col = col0 + wc*BWC + ni*16 + r16;
                    float v = acc[mi][ni][rr];
                    if (MODE == 1) ((float*)Cv)[(size_t)row*ldc + col] = v;
                    else ((unsigned short*)Cv)[(size_t)row*ldc + col] = f2bf(v);
                }
            }
        }
}

// ---------------- RoPE in place (x4 vectorized); Q pre-scaled by rsqrt(128)*log2(e) ----------------
__global__ __launch_bounds__(256) void k_rope(unsigned short* __restrict__ qkv) {
    int tid = blockIdx.x * 256 + threadIdx.x;   // MTOK*(NH+NKV)*16 threads
    int i4   = (tid & 15) * 4;                  // first rotation-pair index of this thread
    int rest = tid >> 4;
    int head = rest % (NH + NKV);
    int tok  = rest / (NH + NKV);
    int pos  = tok & (SEQ - 1);
    size_t base = (size_t)tok * QKLD + head*HD;
    u16x4 a = *(const u16x4*)&qkv[base + i4];
    u16x4 c4 = *(const u16x4*)&qkv[base + i4 + 64];
    float sc = (head < NH) ? 0.12754984523341717f : 1.0f;  // rsqrt(128)*log2(e) folded into Q
    u16x4 oa, ob;
    #pragma unroll
    for (int j = 0; j < 4; ++j) {
        int i = i4 + j;
        float x1 = bf2f(a[j]);
        float x2 = bf2f(c4[j]);
        float inv = exp2f(-0.20762050593046014f * (float)i);   // 10000^(-i/64)
        float ang = (float)pos * inv;
        float s, c;
        sincosf(ang, &s, &c);
        oa[j] = f2bf((x1*c - x2*s) * sc);
        ob[j] = f2bf((x2*c + x1*s) * sc);
    }
    *(u16x4*)&qkv[base + i4]      = oa;
    *(u16x4*)&qkv[base + i4 + 64] = ob;
}

// ---------------- causal GQA flash attention v6 (one chunk per block) — validated R10/R14/R16 ----------------
__global__ __launch_bounds__(256, 2) void k_attn(const unsigned short* __restrict__ qkv,
                                                 const unsigned short* __restrict__ Vt,
                                                 unsigned short* __restrict__ attn_out) {
    __shared__ __align__(16) char KVs[2][32768];   // [buf]: K [64][128] @256B rows | V [128][64] @128B rows
    int bid = blockIdx.x;
    int half = bid >> 8;
    int rem  = bid & 255;
    int xcd = rem & 7, idx = rem >> 3;             // 32 slots per XCD per half
    int bh  = xcd * 4 + (idx >> 3);                // [0,32): 4 bh per XCD (L2 locality)
    int p   = idx & 7;
    int qt  = half ? (15 - p) : p;                 // complementary across the two halves
    int b = bh >> 4, h = bh & 15, kvh = h >> 1;
    int tid = threadIdx.x, wave = tid >> 6, lane = tid & 63;
    int l31 = lane & 31, hi = lane >> 5;
    int nt = 2*qt + 2;                             // kv-tiles for this chunk
    int q0w = qt*128 + wave*32;
    int qg  = q0w + l31;
    const unsigned short* qbase = qkv + (size_t)(b*SEQ)*QKLD;
    const char* kbase = (const char*)(qbase + DIMX + kvh*HD);                    // + row*QKLD*2
    const char* vbase = (const char*)(Vt + ((size_t)(b*NKV + kvh)*HD)*SEQ);      // + d*SEQ*2

    bf16x8 qf[8];
    {
        const unsigned short* qr = qbase + (size_t)qg*QKLD + h*HD;
        #pragma unroll
        for (int s2 = 0; s2 < 8; ++s2) qf[s2] = *(const bf16x8*)(qr + s2*16 + hi*8);
    }

    f32x16 acc[4] = {};                            // O^T: d = 32dt + (r&3)+8(r>>2)+4hi, q = l31
    float mrow = -1e30f, lrow = 0.f;

    auto STAGE = [&](int v, int buf) {
        int kv0 = v * 64;
        char* KL = KVs[buf];
        char* VL = KL + 16384;
        #pragma unroll
        for (int pp = 0; pp < 4; ++pp) {
            int c = wave*4 + pp;
            int row  = c*4 + (lane >> 4);
            int colb = ((lane & 15) * 16) ^ ((row & 7) << 4);
            gload16(kbase + (size_t)(kv0 + row)*(QKLD*2) + colb, KL + c*1024);
            int d    = c*8 + (lane >> 3);
            int colv = ((lane & 7) * 16) ^ ((d & 7) << 4);
            gload16(vbase + (size_t)d*(SEQ*2) + (size_t)kv0*2 + colv, VL + c*1024);
        }
    };

    STAGE(0, 0);
    asm volatile("s_waitcnt vmcnt(0)" ::: "memory");
    __syncthreads();

    for (int v = 0; v < nt; ++v) {
        int buf = v & 1;
        int kv0 = v * 64;
        if (v + 1 < nt) STAGE(v + 1, buf ^ 1);      // loads fly under this tile's compute
        const char* KL = KVs[buf];
        const char* VL = KL + 16384;
        if (kv0 <= q0w + 31) {
            f32x16 st0 = {}, st1 = {};
            const char* kr0 = KL + l31*256;
            const char* kr1 = KL + (32 + l31)*256;
            unsigned sw = (unsigned)((l31 & 7) << 4);
            __builtin_amdgcn_s_setprio(1);
            #pragma unroll
            for (int s2 = 0; s2 < 8; ++s2) {
                unsigned off = (unsigned)(s2*32 + hi*16);
                bf16x8 kf0 = *(const bf16x8*)(kr0 + (off ^ sw));
                bf16x8 kf1 = *(const bf16x8*)(kr1 + (off ^ sw));
                st0 = __builtin_amdgcn_mfma_f32_32x32x16_bf16(kf0, qf[s2], st0, 0, 0, 0);
                st1 = __builtin_amdgcn_mfma_f32_32x32x16_bf16(kf1, qf[s2], st1, 0, 0, 0);
            }
            __builtin_amdgcn_s_setprio(0);
            if (kv0 + 63 > q0w) {
                #pragma unroll
                for (int r = 0; r < 16; ++r) {
                    int kvr = kv0 + (r & 3) + 8*(r >> 2) + 4*hi;
                    st0[r] = (kvr      <= qg) ? st0[r] : -1e30f;
                    st1[r] = (kvr + 32 <= qg) ? st1[r] : -1e30f;
                }
            }
            float mt = -1e30f;
            #pragma unroll
            for (int r = 0; r < 16; ++r) { mt = fmaxf(mt, st0[r]); mt = fmaxf(mt, st1[r]); }
            mt = fmaxf(mt, __shfl_xor(mt, 32, 64));
            if (!__all(mt - mrow <= 8.0f)) {
                float mn = fmaxf(mrow, mt);
                float corr = exp2f(mrow - mn);
                mrow = mn; lrow *= corr;
                #pragma unroll
                for (int dt = 0; dt < 4; ++dt)
                    #pragma unroll
                    for (int r = 0; r < 16; ++r) acc[dt][r] *= corr;
            }
            float rs = 0.f;
            #pragma unroll
            for (int r = 0; r < 16; ++r) {
                float p0 = exp2f(st0[r] - mrow); st0[r] = p0; rs += p0;
                float p1 = exp2f(st1[r] - mrow); st1[r] = p1; rs += p1;
            }
            lrow += rs + __shfl_xor(rs, 32, 64);
            #pragma unroll
            for (int t = 0; t < 2; ++t)
                #pragma unroll
                for (int ks = 0; ks < 2; ++ks) {
                    const f32x16& stt = t ? st1 : st0;
                    int rb = ks * 8;
                    float p0 = stt[rb+0], p1 = stt[rb+1], p2 = stt[rb+2], p3 = stt[rb+3];
                    float p4 = stt[rb+4], p5 = stt[rb+5], p6 = stt[rb+6], p7 = stt[rb+7];
                    unsigned w0, w1, w2, w3;
                    asm("v_cvt_pk_bf16_f32 %0, %1, %2" : "=v"(w0) : "v"(p0), "v"(p1));
                    asm("v_cvt_pk_bf16_f32 %0, %1, %2" : "=v"(w1) : "v"(p2), "v"(p3));
                    asm("v_cvt_pk_bf16_f32 %0, %1, %2" : "=v"(w2) : "v"(p4), "v"(p5));
                    asm("v_cvt_pk_bf16_f32 %0, %1, %2" : "=v"(w3) : "v"(p6), "v"(p7));
                    asm("v_permlane32_swap_b32 %0, %1" : "+v"(w0), "+v"(w2));
                    asm("v_permlane32_swap_b32 %0, %1" : "+v"(w1), "+v"(w3));
                    u32x4 pu = {w0, w1, w2, w3};
                    bf16x8 pfrag = __builtin_bit_cast(bf16x8, pu);
                    int ks4 = t*2 + ks;
                    __builtin_amdgcn_s_setprio(1);
                    #pragma unroll
                    for (int dt = 0; dt < 4; ++dt) {
                        int d = dt*32 + l31;
                        bf16x8 vf = *(const bf16x8*)(VL + d*128 +
                                     (((unsigned)(ks4*32 + hi*16)) ^ ((unsigned)((d & 7) << 4))));
                        acc[dt] = __builtin_amdgcn_mfma_f32_32x32x16_bf16(vf, pfrag, acc[dt], 0, 0, 0);
                    }
                    __builtin_amdgcn_s_setprio(0);
                }
        }
        asm volatile("s_waitcnt vmcnt(0)" ::: "memory");   // next tile landed block-wide
        __syncthreads();
    }

    // ---- epilogue: normalize (lane-local), write bf16, 8B stores ----
    float inv = 1.0f / lrow;
    #pragma unroll
    for (int dt = 0; dt < 4; ++dt)
        #pragma unroll
        for (int qd = 0; qd < 4; ++qd) {
            u16x4 o4;
            #pragma unroll
            for (int j = 0; j < 4; ++j) o4[j] = f2bf(acc[dt][qd*4 + j] * inv);
            *(u16x4*)&attn_out[(size_t)(b*SEQ + qg)*DIMX + h*HD + dt*32 + qd*8 + hi*4] = o4;
        }
}

extern "C" void kernel_launch(void* const* d_in, const int* in_sizes, int n_in,
                              void* d_out, int out_size, void* d_ws, size_t ws_size,
                              hipStream_t stream) {
    const float* x  = (const float*)d_in[0];
    const float* Wq = (const float*)d_in[1];
    const float* Wk = (const float*)d_in[2];
    const float* Wv = (const float*)d_in[3];
    const float* Wo = (const float*)d_in[4];

    // ws layout (all u16), total 92.3 MB
    unsigned short* xb   = (unsigned short*)d_ws;                 // 4096x2048
    unsigned short* Wtq  = xb  + (size_t)MTOK*DIMX;               // 4096x2048 (QKV weights, NxK)
    unsigned short* Wto  = Wtq + (size_t)NQKV*DIMX;               // 2048x2048 (Wo^T)
    unsigned short* qkv  = Wto + (size_t)DIMX*DIMX;               // 4096x3072 (Q|K, ld 3072)
    unsigned short* aout = qkv + (size_t)MTOK*QKLD;               // 4096x2048
    unsigned short* Vt   = aout + (size_t)MTOK*DIMX;              // [2][8][128][2048]

    k_convert<<<(MTOK*DIMX/8 + 255)/256, 256, 0, stream>>>(x, xb, MTOK*DIMX/8);

    // all four weight transposes in one launch (3072 blocks)
    k_transpose_all<<<3072, 256, 0, stream>>>(Wq, Wk, Wv, Wo, Wtq, Wto);

    // GEMM1: 4096x4096x2048, 256x256 tiles -> 256 blocks
    k_gemm256<4, 0><<<256, 512, 0, stream>>>(xb, Wtq, qkv, Vt, MTOK, NQKV, DIMX, QKLD);

    k_rope<<<(MTOK*(NH+NKV)*16)/256, 256, 0, stream>>>(qkv);

    k_attn<<<512, 256, 0, stream>>>(qkv, Vt, aout);

    // GEMM2: 4096x2048x2048, 256x128 tiles -> 256 blocks
    k_gemm256<2, 1><<<256, 512, 0, stream>>>(aout, Wto, (float*)d_out, nullptr, MTOK, DIMX, DIMX, DIMX);
}

// Round 18
// 207.265 us; speedup vs baseline: 1.5822x; 1.0055x over previous
//
#include <hip/hip_runtime.h>

// Problem constants
#define DIMX 2048
#define SEQ  2048
#define BATCH 2
#define NH   16
#define NKV  8
#define HD   128
#define MTOK (BATCH*SEQ)   // 4096 tokens
#define NQKV 4096          // GEMM1 output cols: 2048 Q + 1024 K + 1024 V
#define QKLD 3072          // qkv buffer stride (Q+K only; V goes to Vt)

typedef __bf16 bf16x8 __attribute__((ext_vector_type(8)));
typedef float  f32x4  __attribute__((ext_vector_type(4)));
typedef float  f32x16 __attribute__((ext_vector_type(16)));
typedef unsigned short u16x8 __attribute__((ext_vector_type(8)));
typedef unsigned short u16x4 __attribute__((ext_vector_type(4)));
typedef unsigned int   u32x4 __attribute__((ext_vector_type(4)));

__device__ __forceinline__ unsigned short f2bf(float f) {
    unsigned u = __builtin_bit_cast(unsigned, f);
    u += 0x7fffu + ((u >> 16) & 1u);            // RNE
    return (unsigned short)(u >> 16);
}
__device__ __forceinline__ float bf2f(unsigned short h) {
    unsigned u = ((unsigned)h) << 16;
    return __builtin_bit_cast(float, u);
}

__device__ __forceinline__ void gload16(const void* g, void* l) {
    __builtin_amdgcn_global_load_lds(
        (const __attribute__((address_space(1))) unsigned int*)g,
        (__attribute__((address_space(3))) unsigned int*)l, 16, 0, 0);
}

// ---------------- merged prep: x fp32->bf16 convert + all 4 weight transposes ----------------
// Grid 7168: blocks [0,4096) convert x (8 elems/thread); [4096,7168) transpose 64x64 tiles
// (float4 loads, u16x4 stores). Independent data -> safe to fuse into one launch.
__global__ __launch_bounds__(256) void k_prep(const float* __restrict__ x,
                                              unsigned short* __restrict__ xb,
                                              const float* __restrict__ Wq,
                                              const float* __restrict__ Wk,
                                              const float* __restrict__ Wv,
                                              const float* __restrict__ Wo,
                                              unsigned short* __restrict__ Wtq,
                                              unsigned short* __restrict__ Wto) {
    int bid = blockIdx.x;
    int t = threadIdx.x;
    if (bid < 4096) {                        // ---- convert ----
        int i = bid * 256 + t;               // MTOK*DIMX/8 = 1048576 threads
        f32x4 a = ((const f32x4*)x)[(size_t)i*2];
        f32x4 b = ((const f32x4*)x)[(size_t)i*2+1];
        u16x8 o;
        o[0]=f2bf(a[0]); o[1]=f2bf(a[1]); o[2]=f2bf(a[2]); o[3]=f2bf(a[3]);
        o[4]=f2bf(b[0]); o[5]=f2bf(b[1]); o[6]=f2bf(b[2]); o[7]=f2bf(b[3]);
        ((u16x8*)xb)[i] = o;
        return;
    }
    // ---- transpose ----
    __shared__ unsigned short tile[64*65];
    int tb = bid - 4096;
    const float* W; unsigned short* Wt; int N, n0, k0;
    if (tb < 1024)      { W = Wq; Wt = Wtq;                       N = 2048; int s = tb;        n0 = (s & 31)*64; k0 = (s >> 5)*64; }
    else if (tb < 1536) { W = Wk; Wt = Wtq + (size_t)2048*DIMX;   N = 1024; int s = tb - 1024; n0 = (s & 15)*64; k0 = (s >> 4)*64; }
    else if (tb < 2048) { W = Wv; Wt = Wtq + (size_t)3072*DIMX;   N = 1024; int s = tb - 1536; n0 = (s & 15)*64; k0 = (s >> 4)*64; }
    else                { W = Wo; Wt = Wto;                       N = 2048; int s = tb - 2048; n0 = (s & 31)*64; k0 = (s >> 5)*64; }
    #pragma unroll
    for (int i = 0; i < 4; ++i) {
        int idx = t + i*256;                 // 1024 float4 slots = 64 rows x 16
        int r = idx >> 4, c4 = (idx & 15)*4;
        f32x4 v = *(const f32x4*)&W[(size_t)(k0 + r)*N + n0 + c4];
        tile[r*65 + c4 + 0] = f2bf(v[0]);
        tile[r*65 + c4 + 1] = f2bf(v[1]);
        tile[r*65 + c4 + 2] = f2bf(v[2]);
        tile[r*65 + c4 + 3] = f2bf(v[3]);
    }
    __syncthreads();
    #pragma unroll
    for (int i = 0; i < 4; ++i) {
        int idx = t + i*256;                 // 1024 u16x4 slots = 64 n-rows x 16
        int n = idx >> 4, k4 = (idx & 15)*4;
        u16x4 o4;
        #pragma unroll
        for (int j = 0; j < 4; ++j) o4[j] = tile[(k4 + j)*65 + n];
        *(u16x4*)&Wt[(size_t)(n0 + n)*DIMX + k0 + k4] = o4;
    }
}

// ---------------- 256-wide bf16 GEMM: BMx(NREP*64) tile, BK=64, 8 waves (2Mx4N) ----------------
template<int NREP, int MODE>
__global__ __launch_bounds__(512, 2) void k_gemm256(const unsigned short* __restrict__ A,
                                                    const unsigned short* __restrict__ Bt,
                                                    void* __restrict__ Cv,
                                                    unsigned short* __restrict__ Vt,
                                                    int M, int N, int K, int ldc) {
    constexpr int BN  = NREP * 64;     // 256 or 128
    constexpr int BWC = NREP * 16;     // per-wave col span
    __shared__ __align__(16) char As[2][32768];
    __shared__ __align__(16) char Bs[2][BN * 128];
    int bid = blockIdx.x;
    int rem = (bid & 7) * 32 + (bid >> 3);      // T1 bijective XCD swizzle (nwg=256)
    int bx = rem & 15, by = rem >> 4;
    int row0 = by * 256, col0 = bx * BN;
    int tid = threadIdx.x, wave = tid >> 6, lane = tid & 63;
    int wr = wave >> 2, wc = wave & 3;
    int g = lane >> 4, r16 = lane & 15;
    const char* Ab = (const char*)A;
    const char* Bb = (const char*)Bt;

    f32x4 acc[8][NREP] = {};

    auto STAGE = [&](int buf, int t) {
        int k0b = t * 128;                       // byte offset into K (64 elems * 2B)
        #pragma unroll
        for (int p = 0; p < 4; ++p) {
            int c = wave * 4 + p;
            int o = c * 1024 + lane * 16;
            int row = o >> 7;
            int colb = (o & 127) ^ ((row & 7) << 4);
            gload16(Ab + (size_t)(row0 + row) * (size_t)(K * 2) + k0b + colb, &As[buf][c * 1024]);
        }
        #pragma unroll
        for (int p = 0; p < NREP; ++p) {
            int c = wave * NREP + p;
            int o = c * 1024 + lane * 16;
            int row = o >> 7;
            int colb = (o & 127) ^ ((row & 7) << 4);
            gload16(Bb + (size_t)(col0 + row) * (size_t)(K * 2) + k0b + colb, &Bs[buf][c * 1024]);
        }
    };

    int nt = K >> 6;
    STAGE(0, 0);
    STAGE(1, 1);
    if constexpr (NREP == 4) asm volatile("s_waitcnt vmcnt(8)" ::: "memory");
    else                     asm volatile("s_waitcnt vmcnt(6)" ::: "memory");
    __builtin_amdgcn_s_barrier();

    for (int t = 0; t < nt; ++t) {
        int buf = t & 1;
        const char* AL = As[buf];
        const char* BL = Bs[buf];
        bf16x8 a0[4][2], a1[4][2], bfr[NREP][2];
        #pragma unroll
        for (int mi = 0; mi < 4; ++mi)
            #pragma unroll
            for (int s = 0; s < 2; ++s) {
                int r = wr*128 + mi*16 + r16;
                int o = r*128 + s*64 + g*16;
                a0[mi][s] = *(const bf16x8*)(AL + (o ^ ((r & 7) << 4)));
            }
        #pragma unroll
        for (int ni = 0; ni < NREP; ++ni)
            #pragma unroll
            for (int s = 0; s < 2; ++s) {
                int r = wc*BWC + ni*16 + r16;
                int o = r*128 + s*64 + g*16;
                bfr[ni][s] = *(const bf16x8*)(BL + (o ^ ((r & 7) << 4)));
            }
        __builtin_amdgcn_s_setprio(1);
        #pragma unroll
        for (int mi = 0; mi < 4; ++mi)
            #pragma unroll
            for (int ni = 0; ni < NREP; ++ni)
                #pragma unroll
                for (int s = 0; s < 2; ++s)
                    acc[mi][ni] = __builtin_amdgcn_mfma_f32_16x16x32_bf16(a0[mi][s], bfr[ni][s], acc[mi][ni], 0, 0, 0);
        __builtin_amdgcn_s_setprio(0);
        #pragma unroll
        for (int mi = 0; mi < 4; ++mi)
            #pragma unroll
            for (int s = 0; s < 2; ++s) {
                int r = wr*128 + 64 + mi*16 + r16;
                int o = r*128 + s*64 + g*16;
                a1[mi][s] = *(const bf16x8*)(AL + (o ^ ((r & 7) << 4)));
            }
        asm volatile("s_waitcnt lgkmcnt(0)" ::: "memory");
        __builtin_amdgcn_sched_barrier(0);
        __builtin_amdgcn_s_barrier();            // barrier A: block-wide done reading buf
        if (t + 2 < nt) STAGE(buf, t + 2);       // overwrite freed buffer (loads fly under MFMA)
        __builtin_amdgcn_sched_barrier(0);
        __builtin_amdgcn_s_setprio(1);
        #pragma unroll
        for (int mi = 0; mi < 4; ++mi)
            #pragma unroll
            for (int ni = 0; ni < NREP; ++ni)
                #pragma unroll
                for (int s = 0; s < 2; ++s)
                    acc[mi+4][ni] = __builtin_amdgcn_mfma_f32_16x16x32_bf16(a1[mi][s], bfr[ni][s], acc[mi+4][ni], 0, 0, 0);
        __builtin_amdgcn_s_setprio(0);
        if (t + 2 < nt) {
            if constexpr (NREP == 4) asm volatile("s_waitcnt vmcnt(8)" ::: "memory");
            else                     asm volatile("s_waitcnt vmcnt(6)" ::: "memory");
        } else {
            asm volatile("s_waitcnt vmcnt(0)" ::: "memory");
        }
        __builtin_amdgcn_s_barrier();            // barrier B: K-tile t+1 data landed everywhere
    }

    // epilogue
    #pragma unroll
    for (int mi = 0; mi < 8; ++mi)
        #pragma unroll
        for (int ni = 0; ni < NREP; ++ni) {
            if (MODE == 0 && col0 >= 3072) {
                int vcol = col0 + wc*BWC + ni*16 + r16 - 3072;
                int d = vcol & 127, kh = vcol >> 7;
                int row = row0 + wr*128 + mi*16 + g*4;
                int b = row >> 11, s = row & (SEQ-1);
                u16x4 pk;
                #pragma unroll
                for (int rr = 0; rr < 4; ++rr) pk[rr] = f2bf(acc[mi][ni][rr]);
                *(u16x4*)&Vt[((size_t)(b*NKV + kh)*HD + d)*SEQ + s] = pk;
            } else {
                #pragma unroll
                for (int rr = 0; rr < 4; ++rr) {
                    int row = row0 + wr*128 + mi*16 + g*4 + rr;
                    int col = col0 + wc*BWC + ni*16 + r16;
                    float v = acc[mi][ni][rr];
                    if (MODE == 1) ((float*)Cv)[(size_t)row*ldc + col] = v;
                    else ((unsigned short*)Cv)[(size_t)row*ldc + col] = f2bf(v);
                }
            }
        }
}

// ---------------- RoPE in place (x4 vectorized); Q pre-scaled by rsqrt(128)*log2(e) ----------------
__global__ __launch_bounds__(256) void k_rope(unsigned short* __restrict__ qkv) {
    int tid = blockIdx.x * 256 + threadIdx.x;   // MTOK*(NH+NKV)*16 threads
    int i4   = (tid & 15) * 4;                  // first rotation-pair index of this thread
    int rest = tid >> 4;
    int head = rest % (NH + NKV);
    int tok  = rest / (NH + NKV);
    int pos  = tok & (SEQ - 1);
    size_t base = (size_t)tok * QKLD + head*HD;
    u16x4 a = *(const u16x4*)&qkv[base + i4];
    u16x4 c4 = *(const u16x4*)&qkv[base + i4 + 64];
    float sc = (head < NH) ? 0.12754984523341717f : 1.0f;  // rsqrt(128)*log2(e) folded into Q
    u16x4 oa, ob;
    #pragma unroll
    for (int j = 0; j < 4; ++j) {
        int i = i4 + j;
        float x1 = bf2f(a[j]);
        float x2 = bf2f(c4[j]);
        float inv = exp2f(-0.20762050593046014f * (float)i);   // 10000^(-i/64)
        float ang = (float)pos * inv;
        float s, c;
        sincosf(ang, &s, &c);
        oa[j] = f2bf((x1*c - x2*s) * sc);
        ob[j] = f2bf((x2*c + x1*s) * sc);
    }
    *(u16x4*)&qkv[base + i4]      = oa;
    *(u16x4*)&qkv[base + i4 + 64] = ob;
}

// ---------------- causal GQA flash attention v6 (one chunk per block) — validated R10/R14/R16/R17 ----------------
__global__ __launch_bounds__(256, 2) void k_attn(const unsigned short* __restrict__ qkv,
                                                 const unsigned short* __restrict__ Vt,
                                                 unsigned short* __restrict__ attn_out) {
    __shared__ __align__(16) char KVs[2][32768];   // [buf]: K [64][128] @256B rows | V [128][64] @128B rows
    int bid = blockIdx.x;
    int half = bid >> 8;
    int rem  = bid & 255;
    int xcd = rem & 7, idx = rem >> 3;             // 32 slots per XCD per half
    int bh  = xcd * 4 + (idx >> 3);                // [0,32): 4 bh per XCD (L2 locality)
    int p   = idx & 7;
    int qt  = half ? (15 - p) : p;                 // complementary across the two halves
    int b = bh >> 4, h = bh & 15, kvh = h >> 1;
    int tid = threadIdx.x, wave = tid >> 6, lane = tid & 63;
    int l31 = lane & 31, hi = lane >> 5;
    int nt = 2*qt + 2;                             // kv-tiles for this chunk
    int q0w = qt*128 + wave*32;
    int qg  = q0w + l31;
    const unsigned short* qbase = qkv + (size_t)(b*SEQ)*QKLD;
    const char* kbase = (const char*)(qbase + DIMX + kvh*HD);                    // + row*QKLD*2
    const char* vbase = (const char*)(Vt + ((size_t)(b*NKV + kvh)*HD)*SEQ);      // + d*SEQ*2

    bf16x8 qf[8];
    {
        const unsigned short* qr = qbase + (size_t)qg*QKLD + h*HD;
        #pragma unroll
        for (int s2 = 0; s2 < 8; ++s2) qf[s2] = *(const bf16x8*)(qr + s2*16 + hi*8);
    }

    f32x16 acc[4] = {};                            // O^T: d = 32dt + (r&3)+8(r>>2)+4hi, q = l31
    float mrow = -1e30f, lrow = 0.f;

    auto STAGE = [&](int v, int buf) {
        int kv0 = v * 64;
        char* KL = KVs[buf];
        char* VL = KL + 16384;
        #pragma unroll
        for (int pp = 0; pp < 4; ++pp) {
            int c = wave*4 + pp;
            int row  = c*4 + (lane >> 4);
            int colb = ((lane & 15) * 16) ^ ((row & 7) << 4);
            gload16(kbase + (size_t)(kv0 + row)*(QKLD*2) + colb, KL + c*1024);
            int d    = c*8 + (lane >> 3);
            int colv = ((lane & 7) * 16) ^ ((d & 7) << 4);
            gload16(vbase + (size_t)d*(SEQ*2) + (size_t)kv0*2 + colv, VL + c*1024);
        }
    };

    STAGE(0, 0);
    asm volatile("s_waitcnt vmcnt(0)" ::: "memory");
    __syncthreads();

    for (int v = 0; v < nt; ++v) {
        int buf = v & 1;
        int kv0 = v * 64;
        if (v + 1 < nt) STAGE(v + 1, buf ^ 1);      // loads fly under this tile's compute
        const char* KL = KVs[buf];
        const char* VL = KL + 16384;
        if (kv0 <= q0w + 31) {
            f32x16 st0 = {}, st1 = {};
            const char* kr0 = KL + l31*256;
            const char* kr1 = KL + (32 + l31)*256;
            unsigned sw = (unsigned)((l31 & 7) << 4);
            __builtin_amdgcn_s_setprio(1);
            #pragma unroll
            for (int s2 = 0; s2 < 8; ++s2) {
                unsigned off = (unsigned)(s2*32 + hi*16);
                bf16x8 kf0 = *(const bf16x8*)(kr0 + (off ^ sw));
                bf16x8 kf1 = *(const bf16x8*)(kr1 + (off ^ sw));
                st0 = __builtin_amdgcn_mfma_f32_32x32x16_bf16(kf0, qf[s2], st0, 0, 0, 0);
                st1 = __builtin_amdgcn_mfma_f32_32x32x16_bf16(kf1, qf[s2], st1, 0, 0, 0);
            }
            __builtin_amdgcn_s_setprio(0);
            if (kv0 + 63 > q0w) {
                #pragma unroll
                for (int r = 0; r < 16; ++r) {
                    int kvr = kv0 + (r & 3) + 8*(r >> 2) + 4*hi;
                    st0[r] = (kvr      <= qg) ? st0[r] : -1e30f;
                    st1[r] = (kvr + 32 <= qg) ? st1[r] : -1e30f;
                }
            }
            float mt = -1e30f;
            #pragma unroll
            for (int r = 0; r < 16; ++r) { mt = fmaxf(mt, st0[r]); mt = fmaxf(mt, st1[r]); }
            mt = fmaxf(mt, __shfl_xor(mt, 32, 64));
            if (!__all(mt - mrow <= 8.0f)) {
                float mn = fmaxf(mrow, mt);
                float corr = exp2f(mrow - mn);
                mrow = mn; lrow *= corr;
                #pragma unroll
                for (int dt = 0; dt < 4; ++dt)
                    #pragma unroll
                    for (int r = 0; r < 16; ++r) acc[dt][r] *= corr;
            }
            float rs = 0.f;
            #pragma unroll
            for (int r = 0; r < 16; ++r) {
                float p0 = exp2f(st0[r] - mrow); st0[r] = p0; rs += p0;
                float p1 = exp2f(st1[r] - mrow); st1[r] = p1; rs += p1;
            }
            lrow += rs + __shfl_xor(rs, 32, 64);
            #pragma unroll
            for (int t = 0; t < 2; ++t)
                #pragma unroll
                for (int ks = 0; ks < 2; ++ks) {
                    const f32x16& stt = t ? st1 : st0;
                    int rb = ks * 8;
                    float p0 = stt[rb+0], p1 = stt[rb+1], p2 = stt[rb+2], p3 = stt[rb+3];
                    float p4 = stt[rb+4], p5 = stt[rb+5], p6 = stt[rb+6], p7 = stt[rb+7];
                    unsigned w0, w1, w2, w3;
                    asm("v_cvt_pk_bf16_f32 %0, %1, %2" : "=v"(w0) : "v"(p0), "v"(p1));
                    asm("v_cvt_pk_bf16_f32 %0, %1, %2" : "=v"(w1) : "v"(p2), "v"(p3));
                    asm("v_cvt_pk_bf16_f32 %0, %1, %2" : "=v"(w2) : "v"(p4), "v"(p5));
                    asm("v_cvt_pk_bf16_f32 %0, %1, %2" : "=v"(w3) : "v"(p6), "v"(p7));
                    asm("v_permlane32_swap_b32 %0, %1" : "+v"(w0), "+v"(w2));
                    asm("v_permlane32_swap_b32 %0, %1" : "+v"(w1), "+v"(w3));
                    u32x4 pu = {w0, w1, w2, w3};
                    bf16x8 pfrag = __builtin_bit_cast(bf16x8, pu);
                    int ks4 = t*2 + ks;
                    __builtin_amdgcn_s_setprio(1);
                    #pragma unroll
                    for (int dt = 0; dt < 4; ++dt) {
                        int d = dt*32 + l31;
                        bf16x8 vf = *(const bf16x8*)(VL + d*128 +
                                     (((unsigned)(ks4*32 + hi*16)) ^ ((unsigned)((d & 7) << 4))));
                        acc[dt] = __builtin_amdgcn_mfma_f32_32x32x16_bf16(vf, pfrag, acc[dt], 0, 0, 0);
                    }
                    __builtin_amdgcn_s_setprio(0);
                }
        }
        asm volatile("s_waitcnt vmcnt(0)" ::: "memory");   // next tile landed block-wide
        __syncthreads();
    }

    // ---- epilogue: normalize (lane-local), write bf16, 8B stores ----
    float inv = 1.0f / lrow;
    #pragma unroll
    for (int dt = 0; dt < 4; ++dt)
        #pragma unroll
        for (int qd = 0; qd < 4; ++qd) {
            u16x4 o4;
            #pragma unroll
            for (int j = 0; j < 4; ++j) o4[j] = f2bf(acc[dt][qd*4 + j] * inv);
            *(u16x4*)&attn_out[(size_t)(b*SEQ + qg)*DIMX + h*HD + dt*32 + qd*8 + hi*4] = o4;
        }
}

extern "C" void kernel_launch(void* const* d_in, const int* in_sizes, int n_in,
                              void* d_out, int out_size, void* d_ws, size_t ws_size,
                              hipStream_t stream) {
    const float* x  = (const float*)d_in[0];
    const float* Wq = (const float*)d_in[1];
    const float* Wk = (const float*)d_in[2];
    const float* Wv = (const float*)d_in[3];
    const float* Wo = (const float*)d_in[4];

    // ws layout (all u16), total 92.3 MB
    unsigned short* xb   = (unsigned short*)d_ws;                 // 4096x2048
    unsigned short* Wtq  = xb  + (size_t)MTOK*DIMX;               // 4096x2048 (QKV weights, NxK)
    unsigned short* Wto  = Wtq + (size_t)NQKV*DIMX;               // 2048x2048 (Wo^T)
    unsigned short* qkv  = Wto + (size_t)DIMX*DIMX;               // 4096x3072 (Q|K, ld 3072)
    unsigned short* aout = qkv + (size_t)MTOK*QKLD;               // 4096x2048
    unsigned short* Vt   = aout + (size_t)MTOK*DIMX;              // [2][8][128][2048]

    // prep: x convert + all weight transposes in one launch
    k_prep<<<7168, 256, 0, stream>>>(x, xb, Wq, Wk, Wv, Wo, Wtq, Wto);

    // GEMM1: 4096x4096x2048, 256x256 tiles -> 256 blocks
    k_gemm256<4, 0><<<256, 512, 0, stream>>>(xb, Wtq, qkv, Vt, MTOK, NQKV, DIMX, QKLD);

    k_rope<<<(MTOK*(NH+NKV)*16)/256, 256, 0, stream>>>(qkv);

    k_attn<<<512, 256, 0, stream>>>(qkv, Vt, aout);

    // GEMM2: 4096x2048x2048, 256x128 tiles -> 256 blocks
    k_gemm256<2, 1><<<256, 512, 0, stream>>>(aout, Wto, (float*)d_out, nullptr, MTOK, DIMX, DIMX, DIMX);
}